// Round 6
// baseline (165.966 us; speedup 1.0000x reference)
//
#include <hip/hip_runtime.h>
#include <hip/hip_fp16.h>

#define IN_F 128
#define OUT_F 64
#define NB    256     // node-range buckets, 512 nodes each
#define BSH   9
#define CAP   3840    // per-bucket capacity (lambda=2344, +31 sigma, proven R4-R7)
#define CHUNK 2048    // edges per bin block
#define KPF  136      // Fh k-pitch (bf16 elems)
#define KPW  144      // Wt k-pitch (bf16 elems)

using short8  = __attribute__((ext_vector_type(8))) short;
using float4v = __attribute__((ext_vector_type(4))) float;

static __device__ inline unsigned short f2bf(float x) {
    union { float f; unsigned u; } v; v.f = x;
    unsigned r = (v.u + 0x7fffu + ((v.u >> 16) & 1u)) >> 16;  // RN-even
    return (unsigned short)r;
}

// ---- fused pass 1: edge binning (blocks 0..nbin-1)  ||  GEMM (rest) --------
// (byte-identical to R3/R5's proven kernel)
__global__ __launch_bounds__(256) void bin_gemm_kernel(
    const int* __restrict__ src, const int* __restrict__ dst,
    int* __restrict__ gcur_d, int* __restrict__ gcur_s,
    unsigned* __restrict__ bkt_d, unsigned short* __restrict__ bkt_s,
    int E, int nbin,
    const float* __restrict__ feat, const float* __restrict__ W,
    __half* __restrict__ h, int n)
{
    __shared__ union {
        struct { int hd[NB]; int hs[NB]; int based[NB]; int bases[NB]; } bin;
        struct { unsigned short Fh[128 * KPF]; unsigned short Wt[64 * KPW]; } gm;
    } smem;

    const int tid = threadIdx.x;

    if (blockIdx.x < (unsigned)nbin) {
        const int e0 = blockIdx.x * CHUNK;

        smem.bin.hd[tid] = 0; smem.bin.hs[tid] = 0;
        __syncthreads();

        int sv[8], dv[8];
        #pragma unroll
        for (int j = 0; j < 8; ++j) {
            int i = e0 + j * 256 + tid;          // coalesced
            if (i < E) { sv[j] = src[i]; dv[j] = dst[i]; }
            else       { sv[j] = -1;     dv[j] = -1; }
        }
        #pragma unroll
        for (int j = 0; j < 8; ++j) {
            if (dv[j] >= 0) {
                atomicAdd(&smem.bin.hd[dv[j] >> BSH], 1);
                atomicAdd(&smem.bin.hs[sv[j] >> BSH], 1);
            }
        }
        __syncthreads();

        int cd = smem.bin.hd[tid], cs = smem.bin.hs[tid];
        smem.bin.based[tid] = cd ? atomicAdd(&gcur_d[tid], cd) : 0;
        smem.bin.bases[tid] = cs ? atomicAdd(&gcur_s[tid], cs) : 0;
        smem.bin.hd[tid] = 0; smem.bin.hs[tid] = 0;   // reuse as local cursors
        __syncthreads();

        #pragma unroll
        for (int j = 0; j < 8; ++j) {
            if (dv[j] >= 0) {
                int bd = dv[j] >> BSH;
                int pd = atomicAdd(&smem.bin.hd[bd], 1) + smem.bin.based[bd];
                if (pd < CAP)
                    bkt_d[(size_t)bd * CAP + pd] =
                        (unsigned)sv[j] | ((unsigned)(dv[j] & 511) << 17);  // src < 2^17
                int bs = sv[j] >> BSH;
                int ps = atomicAdd(&smem.bin.hs[bs], 1) + smem.bin.bases[bs];
                if (ps < CAP) bkt_s[(size_t)bs * CAP + ps] = (unsigned short)(sv[j] & 511);
            }
        }
        return;
    }

    // ---------------- gemm path: h = feat @ W (raw fp16; ns applied in gather)
    unsigned short* Fh = smem.gm.Fh;
    unsigned short* Wt = smem.gm.Wt;
    const int row0 = (blockIdx.x - nbin) * 128;

    {
        const float4* W4 = (const float4*)W;
        #pragma unroll
        for (int it = 0; it < 8; ++it) {
            int i4 = it * 256 + tid;
            int k  = i4 >> 4;
            int c4 = (i4 & 15) * 4;
            float4 wv = W4[i4];
            Wt[(c4 + 0) * KPW + k] = f2bf(wv.x);
            Wt[(c4 + 1) * KPW + k] = f2bf(wv.y);
            Wt[(c4 + 2) * KPW + k] = f2bf(wv.z);
            Wt[(c4 + 3) * KPW + k] = f2bf(wv.w);
        }
    }
    {
        const float4* F4 = (const float4*)feat;
        #pragma unroll
        for (int it = 0; it < 16; ++it) {
            int i4 = it * 256 + tid;
            int r  = i4 >> 5;
            int c4 = (i4 & 31) * 4;
            int gr = row0 + r; if (gr >= n) gr = n - 1;
            float4 v = F4[(long)gr * 32 + (i4 & 31)];
            ushort4 u;
            u.x = f2bf(v.x); u.y = f2bf(v.y); u.z = f2bf(v.z); u.w = f2bf(v.w);
            *(ushort4*)&Fh[r * KPF + c4] = u;
        }
    }
    __syncthreads();

    const int w  = tid >> 6;
    const int l  = tid & 63;
    const int ml = l & 15;
    const int q  = l >> 4;

    float4v acc[2][4];
    #pragma unroll
    for (int rt = 0; rt < 2; ++rt)
        #pragma unroll
        for (int ct = 0; ct < 4; ++ct)
            acc[rt][ct] = (float4v){0.f, 0.f, 0.f, 0.f};

    #pragma unroll
    for (int ks = 0; ks < 4; ++ks) {
        const int ko = ks * 32 + q * 8;
        short8 a0 = *(const short8*)&Fh[(w * 32 +  0 + ml) * KPF + ko];
        short8 a1 = *(const short8*)&Fh[(w * 32 + 16 + ml) * KPF + ko];
        short8 b0 = *(const short8*)&Wt[( 0 + ml) * KPW + ko];
        short8 b1 = *(const short8*)&Wt[(16 + ml) * KPW + ko];
        short8 b2 = *(const short8*)&Wt[(32 + ml) * KPW + ko];
        short8 b3 = *(const short8*)&Wt[(48 + ml) * KPW + ko];
        acc[0][0] = __builtin_amdgcn_mfma_f32_16x16x32_bf16(a0, b0, acc[0][0], 0, 0, 0);
        acc[0][1] = __builtin_amdgcn_mfma_f32_16x16x32_bf16(a0, b1, acc[0][1], 0, 0, 0);
        acc[0][2] = __builtin_amdgcn_mfma_f32_16x16x32_bf16(a0, b2, acc[0][2], 0, 0, 0);
        acc[0][3] = __builtin_amdgcn_mfma_f32_16x16x32_bf16(a0, b3, acc[0][3], 0, 0, 0);
        acc[1][0] = __builtin_amdgcn_mfma_f32_16x16x32_bf16(a1, b0, acc[1][0], 0, 0, 0);
        acc[1][1] = __builtin_amdgcn_mfma_f32_16x16x32_bf16(a1, b1, acc[1][1], 0, 0, 0);
        acc[1][2] = __builtin_amdgcn_mfma_f32_16x16x32_bf16(a1, b2, acc[1][2], 0, 0, 0);
        acc[1][3] = __builtin_amdgcn_mfma_f32_16x16x32_bf16(a1, b3, acc[1][3], 0, 0, 0);
    }

    #pragma unroll
    for (int rt = 0; rt < 2; ++rt) {
        #pragma unroll
        for (int reg = 0; reg < 4; ++reg) {
            int row = row0 + w * 32 + rt * 16 + q * 4 + reg;
            if (row < n) {
                #pragma unroll
                for (int ct = 0; ct < 4; ++ct)
                    h[(long)row * OUT_F + ct * 16 + ml] = __float2half(acc[rt][ct][reg]);
            }
        }
    }
}

// ---- pass 2: nsrc = rsqrt(max(outdeg,1)) via per-bucket src histogram ------
// (R4's proven outdeg kernel, writing the rsqrt float directly)
__global__ __launch_bounds__(256) void outdeg_kernel(
    const unsigned short* __restrict__ bkt_s, const int* __restrict__ gcur_s,
    float* __restrict__ nsrc, int n)
{
    __shared__ int hs[512];
    const int b = blockIdx.x, tid = threadIdx.x;
    const int cnt_s = min(gcur_s[b], CAP);

    hs[tid] = 0; hs[tid + 256] = 0;
    __syncthreads();

    const unsigned short* bp = bkt_s + (size_t)b * CAP;
    for (int i = tid; i < cnt_s; i += 256)
        atomicAdd(&hs[bp[i]], 1);
    __syncthreads();

    int node = b * 512 + tid;
    if (node < n) nsrc[node] = rsqrtf(fmaxf((float)hs[tid], 1.0f));
    node += 256;
    if (node < n) nsrc[node] = rsqrtf(fmaxf((float)hs[tid + 256], 1.0f));
}

// ---- pass 3: fused sort+gather. Block b sorts its bucket's edges by dst
// INTO LDS (elist, 15.4 KB), then 16 waves gather 32 dsts each straight from
// LDS. Removes the ebuf/off_deg global round-trip, the csr->gather kernel
// boundary, and the per-dst-wave launch overhead of the old 25000-block gather.
__global__ __launch_bounds__(1024) void sortgather_kernel(
    const unsigned* __restrict__ bkt_d, const int* __restrict__ gcur_d,
    const float* __restrict__ nsrc,
    const __half* __restrict__ h, float* __restrict__ out, int n)
{
    __shared__ int sstart[512];     // per-dl exclusive start
    __shared__ int sdeg[512];       // per-dl degree (hist)
    __shared__ int curs[512];       // scatter cursors
    __shared__ int wsum[8];
    __shared__ int elist[CAP];      // sorted src ids (15.4 KB)

    const int b = blockIdx.x, tid = threadIdx.x;
    const int cnt = min(gcur_d[b], CAP);
    const unsigned* bp = bkt_d + (size_t)b * CAP;

    if (tid < 512) sdeg[tid] = 0;
    __syncthreads();

    // histogram dst-locals (bucket window <=15 KB, coalesced)
    for (int i = tid; i < cnt; i += 1024)
        atomicAdd(&sdeg[bp[i] >> 17], 1);
    __syncthreads();

    // exclusive scan of sdeg[512]: shuffle scan in waves 0..7 + combine
    const int lane = tid & 63;
    int deg = (tid < 512) ? sdeg[tid] : 0;
    int x = deg;
    #pragma unroll
    for (int off = 1; off < 64; off <<= 1) {
        int y = __shfl_up(x, off);
        if (lane >= off) x += y;
    }
    if (tid < 512 && lane == 63) wsum[tid >> 6] = x;
    __syncthreads();
    if (tid < 512) {
        int wv = tid >> 6, wbase = 0;
        for (int i = 0; i < wv; ++i) wbase += wsum[i];
        int excl = x + wbase - deg;
        sstart[tid] = excl;
        curs[tid]   = excl;
    }
    __syncthreads();

    // sorted scatter into LDS (bucket window re-read is L1/L2-hot)
    for (int i = tid; i < cnt; i += 1024) {
        unsigned e = bp[i];
        int p = atomicAdd(&curs[e >> 17], 1);
        if (p < CAP) elist[p] = (int)(e & 0x1FFFFu);
    }
    __syncthreads();

    // gather: wave wv handles dls wv, wv+16, ... (32 each)
    const int wv = tid >> 6;
    const int o  = lane >> 3;       // edge stream 0..7
    const int t  = lane & 7;        // covers cols 8t..8t+7
    for (int dl = wv; dl < 512; dl += 16) {
        int node = b * 512 + dl;
        if (node >= n) break;       // wave-uniform (dl uniform per wave)
        int beg = sstart[dl], m = sdeg[dl], end = beg + m;
        float a0 = 0.f, a1 = 0.f, a2 = 0.f, a3 = 0.f;
        float a4 = 0.f, a5 = 0.f, a6 = 0.f, a7 = 0.f;
        for (int j = beg + o; j < end; j += 8) {
            int s = elist[j];                 // LDS, broadcast within stream
            float ns = nsrc[s];               // 400 KB L2-resident table
            union { uint4 u; __half2 h2[4]; } P;
            P.u = *(const uint4*)&h[(long)s * OUT_F + 8 * t];
            float2 f0 = __half22float2(P.h2[0]);
            float2 f1 = __half22float2(P.h2[1]);
            float2 f2 = __half22float2(P.h2[2]);
            float2 f3 = __half22float2(P.h2[3]);
            a0 = fmaf(f0.x, ns, a0); a1 = fmaf(f0.y, ns, a1);
            a2 = fmaf(f1.x, ns, a2); a3 = fmaf(f1.y, ns, a3);
            a4 = fmaf(f2.x, ns, a4); a5 = fmaf(f2.y, ns, a5);
            a6 = fmaf(f3.x, ns, a6); a7 = fmaf(f3.y, ns, a7);
        }
        #pragma unroll
        for (int mask = 8; mask <= 32; mask <<= 1) {
            a0 += __shfl_xor(a0, mask); a1 += __shfl_xor(a1, mask);
            a2 += __shfl_xor(a2, mask); a3 += __shfl_xor(a3, mask);
            a4 += __shfl_xor(a4, mask); a5 += __shfl_xor(a5, mask);
            a6 += __shfl_xor(a6, mask); a7 += __shfl_xor(a7, mask);
        }
        if (o == 0) {
            float nd = rsqrtf(fmaxf((float)m, 1.0f));
            float4 v0 = make_float4(a0 * nd, a1 * nd, a2 * nd, a3 * nd);
            float4 v1 = make_float4(a4 * nd, a5 * nd, a6 * nd, a7 * nd);
            float* op = &out[(long)node * OUT_F + 8 * t];
            *(float4*)op       = v0;
            *(float4*)(op + 4) = v1;
        }
    }
}

extern "C" void kernel_launch(void* const* d_in, const int* in_sizes, int n_in,
                              void* d_out, int out_size, void* d_ws, size_t ws_size,
                              hipStream_t stream) {
    const float* feat = (const float*)d_in[0];
    const float* W    = (const float*)d_in[1];
    const int*   src  = (const int*)d_in[2];
    const int*   dst  = (const int*)d_in[3];
    float* out = (float*)d_out;

    const int n = in_sizes[0] / IN_F;     // 100000
    const int E = in_sizes[2];            // 600000

    // ---- workspace layout (~19 MB; ws is ~268 MB) ----
    char* wsb = (char*)d_ws;
    int* gcur_d = (int*)wsb;                              // NB
    int* gcur_s = gcur_d + NB;                            // NB
    float* nsrc = (float*)(gcur_s + NB);                  // n
    size_t pos = (((size_t)(2 * NB + n)) * 4 + 15) & ~(size_t)15;
    unsigned* bkt_d = (unsigned*)(wsb + pos);             // NB*CAP u32 (3.9 MB)
    pos = (pos + (size_t)NB * CAP * 4 + 15) & ~(size_t)15;
    unsigned short* bkt_s = (unsigned short*)(wsb + pos); // NB*CAP u16 (2.0 MB)
    pos = (pos + (size_t)NB * CAP * 2 + 15) & ~(size_t)15;
    __half* h = (__half*)(wsb + pos);                     // n*64 fp16 (12.8 MB)

    hipMemsetAsync(gcur_d, 0, 2 * NB * sizeof(int), stream);

    const int nbin  = (E + CHUNK - 1) / CHUNK;            // 293
    const int ngemm = (n + 127) / 128;                    // 782

    bin_gemm_kernel<<<nbin + ngemm, 256, 0, stream>>>(src, dst, gcur_d, gcur_s,
                                                      bkt_d, bkt_s, E, nbin,
                                                      feat, W, h, n);
    outdeg_kernel<<<NB, 256, 0, stream>>>(bkt_s, gcur_s, nsrc, n);
    sortgather_kernel<<<NB, 1024, 0, stream>>>(bkt_d, gcur_d, nsrc, h, out, n);
}

// Round 7
// 145.289 us; speedup vs baseline: 1.1423x; 1.1423x over previous
//
#include <hip/hip_runtime.h>
#include <hip/hip_fp16.h>

#define IN_F 128
#define OUT_F 64
#define NB    256     // node-range buckets, 512 nodes each
#define BSH   9
#define CAP   3840    // per-bucket capacity (lambda=2344, +31 sigma, proven R4-R7)
#define CHUNK 2048    // edges per bin block
#define KPF  136      // Fh k-pitch (bf16 elems)
#define KPW  144      // Wt k-pitch (bf16 elems)

using short8  = __attribute__((ext_vector_type(8))) short;
using float4v = __attribute__((ext_vector_type(4))) float;

static __device__ inline unsigned short f2bf(float x) {
    union { float f; unsigned u; } v; v.f = x;
    unsigned r = (v.u + 0x7fffu + ((v.u >> 16) & 1u)) >> 16;  // RN-even
    return (unsigned short)r;
}

// ---- fused pass 1: edge binning (blocks 0..nbin-1)  ||  GEMM (rest) --------
// (byte-identical to R3/R5's proven kernel)
__global__ __launch_bounds__(256) void bin_gemm_kernel(
    const int* __restrict__ src, const int* __restrict__ dst,
    int* __restrict__ gcur_d, int* __restrict__ gcur_s,
    unsigned* __restrict__ bkt_d, unsigned short* __restrict__ bkt_s,
    int E, int nbin,
    const float* __restrict__ feat, const float* __restrict__ W,
    __half* __restrict__ h, int n)
{
    __shared__ union {
        struct { int hd[NB]; int hs[NB]; int based[NB]; int bases[NB]; } bin;
        struct { unsigned short Fh[128 * KPF]; unsigned short Wt[64 * KPW]; } gm;
    } smem;

    const int tid = threadIdx.x;

    if (blockIdx.x < (unsigned)nbin) {
        const int e0 = blockIdx.x * CHUNK;

        smem.bin.hd[tid] = 0; smem.bin.hs[tid] = 0;
        __syncthreads();

        int sv[8], dv[8];
        #pragma unroll
        for (int j = 0; j < 8; ++j) {
            int i = e0 + j * 256 + tid;          // coalesced
            if (i < E) { sv[j] = src[i]; dv[j] = dst[i]; }
            else       { sv[j] = -1;     dv[j] = -1; }
        }
        #pragma unroll
        for (int j = 0; j < 8; ++j) {
            if (dv[j] >= 0) {
                atomicAdd(&smem.bin.hd[dv[j] >> BSH], 1);
                atomicAdd(&smem.bin.hs[sv[j] >> BSH], 1);
            }
        }
        __syncthreads();

        int cd = smem.bin.hd[tid], cs = smem.bin.hs[tid];
        smem.bin.based[tid] = cd ? atomicAdd(&gcur_d[tid], cd) : 0;
        smem.bin.bases[tid] = cs ? atomicAdd(&gcur_s[tid], cs) : 0;
        smem.bin.hd[tid] = 0; smem.bin.hs[tid] = 0;   // reuse as local cursors
        __syncthreads();

        #pragma unroll
        for (int j = 0; j < 8; ++j) {
            if (dv[j] >= 0) {
                int bd = dv[j] >> BSH;
                int pd = atomicAdd(&smem.bin.hd[bd], 1) + smem.bin.based[bd];
                if (pd < CAP)
                    bkt_d[(size_t)bd * CAP + pd] =
                        (unsigned)sv[j] | ((unsigned)(dv[j] & 511) << 17);  // src < 2^17
                int bs = sv[j] >> BSH;
                int ps = atomicAdd(&smem.bin.hs[bs], 1) + smem.bin.bases[bs];
                if (ps < CAP) bkt_s[(size_t)bs * CAP + ps] = (unsigned short)(sv[j] & 511);
            }
        }
        return;
    }

    // ---------------- gemm path: h = feat @ W (raw fp16; ns applied in gather)
    unsigned short* Fh = smem.gm.Fh;
    unsigned short* Wt = smem.gm.Wt;
    const int row0 = (blockIdx.x - nbin) * 128;

    {
        const float4* W4 = (const float4*)W;
        #pragma unroll
        for (int it = 0; it < 8; ++it) {
            int i4 = it * 256 + tid;
            int k  = i4 >> 4;
            int c4 = (i4 & 15) * 4;
            float4 wv = W4[i4];
            Wt[(c4 + 0) * KPW + k] = f2bf(wv.x);
            Wt[(c4 + 1) * KPW + k] = f2bf(wv.y);
            Wt[(c4 + 2) * KPW + k] = f2bf(wv.z);
            Wt[(c4 + 3) * KPW + k] = f2bf(wv.w);
        }
    }
    {
        const float4* F4 = (const float4*)feat;
        #pragma unroll
        for (int it = 0; it < 16; ++it) {
            int i4 = it * 256 + tid;
            int r  = i4 >> 5;
            int c4 = (i4 & 31) * 4;
            int gr = row0 + r; if (gr >= n) gr = n - 1;
            float4 v = F4[(long)gr * 32 + (i4 & 31)];
            ushort4 u;
            u.x = f2bf(v.x); u.y = f2bf(v.y); u.z = f2bf(v.z); u.w = f2bf(v.w);
            *(ushort4*)&Fh[r * KPF + c4] = u;
        }
    }
    __syncthreads();

    const int w  = tid >> 6;
    const int l  = tid & 63;
    const int ml = l & 15;
    const int q  = l >> 4;

    float4v acc[2][4];
    #pragma unroll
    for (int rt = 0; rt < 2; ++rt)
        #pragma unroll
        for (int ct = 0; ct < 4; ++ct)
            acc[rt][ct] = (float4v){0.f, 0.f, 0.f, 0.f};

    #pragma unroll
    for (int ks = 0; ks < 4; ++ks) {
        const int ko = ks * 32 + q * 8;
        short8 a0 = *(const short8*)&Fh[(w * 32 +  0 + ml) * KPF + ko];
        short8 a1 = *(const short8*)&Fh[(w * 32 + 16 + ml) * KPF + ko];
        short8 b0 = *(const short8*)&Wt[( 0 + ml) * KPW + ko];
        short8 b1 = *(const short8*)&Wt[(16 + ml) * KPW + ko];
        short8 b2 = *(const short8*)&Wt[(32 + ml) * KPW + ko];
        short8 b3 = *(const short8*)&Wt[(48 + ml) * KPW + ko];
        acc[0][0] = __builtin_amdgcn_mfma_f32_16x16x32_bf16(a0, b0, acc[0][0], 0, 0, 0);
        acc[0][1] = __builtin_amdgcn_mfma_f32_16x16x32_bf16(a0, b1, acc[0][1], 0, 0, 0);
        acc[0][2] = __builtin_amdgcn_mfma_f32_16x16x32_bf16(a0, b2, acc[0][2], 0, 0, 0);
        acc[0][3] = __builtin_amdgcn_mfma_f32_16x16x32_bf16(a0, b3, acc[0][3], 0, 0, 0);
        acc[1][0] = __builtin_amdgcn_mfma_f32_16x16x32_bf16(a1, b0, acc[1][0], 0, 0, 0);
        acc[1][1] = __builtin_amdgcn_mfma_f32_16x16x32_bf16(a1, b1, acc[1][1], 0, 0, 0);
        acc[1][2] = __builtin_amdgcn_mfma_f32_16x16x32_bf16(a1, b2, acc[1][2], 0, 0, 0);
        acc[1][3] = __builtin_amdgcn_mfma_f32_16x16x32_bf16(a1, b3, acc[1][3], 0, 0, 0);
    }

    #pragma unroll
    for (int rt = 0; rt < 2; ++rt) {
        #pragma unroll
        for (int reg = 0; reg < 4; ++reg) {
            int row = row0 + w * 32 + rt * 16 + q * 4 + reg;
            if (row < n) {
                #pragma unroll
                for (int ct = 0; ct < 4; ++ct)
                    h[(long)row * OUT_F + ct * 16 + ml] = __float2half(acc[rt][ct][reg]);
            }
        }
    }
}

// ---- pass 2: per-bucket counting sort + nsrc + off_deg (R5's proven kernel)
__global__ __launch_bounds__(256) void csr_kernel(
    const unsigned* __restrict__ bkt_d, const unsigned short* __restrict__ bkt_s,
    const int* __restrict__ gcur_d, const int* __restrict__ gcur_s,
    int2* __restrict__ off_deg, int* __restrict__ ebuf, float* __restrict__ nsrc, int n)
{
    __shared__ int hist[512], curs[512], hist_s[512];
    __shared__ int wsum[4];
    const int b = blockIdx.x, tid = threadIdx.x;
    const int cnt   = min(gcur_d[b], CAP);
    const int cnt_s = min(gcur_s[b], CAP);

    hist[tid] = 0; hist[tid + 256] = 0;
    hist_s[tid] = 0; hist_s[tid + 256] = 0;
    __syncthreads();

    const unsigned* bp = bkt_d + (size_t)b * CAP;
    for (int i = tid; i < cnt; i += 256)
        atomicAdd(&hist[bp[i] >> 17], 1);
    // src-side histogram (outdeg for nodes in this bucket's range)
    for (int i = tid; i < cnt_s; i += 256)
        atomicAdd(&hist_s[bkt_s[(size_t)b * CAP + i]], 1);
    __syncthreads();

    // exclusive scan of hist[512]: wave shuffle scan + cross-wave combine
    int a0 = hist[2 * tid], a1 = hist[2 * tid + 1];
    int psum = a0 + a1;
    const int lane = tid & 63, w = tid >> 6;
    int x = psum;
    #pragma unroll
    for (int off = 1; off < 64; off <<= 1) {
        int y = __shfl_up(x, off);
        if (lane >= off) x += y;
    }
    if (lane == 63) wsum[w] = x;
    __syncthreads();
    int wbase = 0;
    for (int i = 0; i < w; ++i) wbase += wsum[i];
    int excl = x + wbase - psum;
    curs[2 * tid]     = excl;
    curs[2 * tid + 1] = excl + a0;
    off_deg[b * 512 + 2 * tid]     = make_int2(b * CAP + excl,      a0);
    off_deg[b * 512 + 2 * tid + 1] = make_int2(b * CAP + excl + a0, a1);
    __syncthreads();

    // sorted scatter straight to global; bucket window re-read is L1/L2-hot
    for (int i = tid; i < cnt; i += 256) {
        unsigned e = bp[i];
        int p = atomicAdd(&curs[e >> 17], 1);
        if (p < CAP) ebuf[b * CAP + p] = (int)(e & 0x1FFFFu);
    }

    // nsrc writeout: precomputed rsqrt so gather loads a plain float table
    int node = b * 512 + tid;
    if (node < n) nsrc[node] = rsqrtf(fmaxf((float)hist_s[tid], 1.0f));
    node += 256;
    if (node < n) nsrc[node] = rsqrtf(fmaxf((float)hist_s[tid + 256], 1.0f));
}

// ---- pull aggregation, stream-per-dst: each 8-lane group owns ONE dst (its
// 8 lanes cover the 64 cols; lane loads 16 B -> full 128 B row per edge).
// Block of 256 thr = 32 consecutive dsts; grid 3125 -> ~12 blocks/CU pipeline.
// Edge loop unrolled x2 with independent load chains -> 2x loads in flight.
// No cross-lane reduce (each group owns its dst fully) -> no shfl_xor at all.
__global__ __launch_bounds__(256) void gather_kernel(
    const int* __restrict__ ebuf, const int2* __restrict__ off_deg,
    const float* __restrict__ nsrc,
    const __half* __restrict__ h, float* __restrict__ out, int n)
{
    const int lane = threadIdx.x & 63;
    const int wv   = threadIdx.x >> 6;     // wave 0..3
    const int o    = lane >> 3;            // stream 0..7 -> dst offset in wave
    const int t    = lane & 7;             // col group: cols 8t..8t+7
    const int d    = blockIdx.x * 32 + wv * 8 + o;
    if (d >= n) return;

    int2 od = off_deg[d];
    const int beg = od.x, m = od.y, end = beg + m;

    float a0 = 0.f, a1 = 0.f, a2 = 0.f, a3 = 0.f;
    float a4 = 0.f, a5 = 0.f, a6 = 0.f, a7 = 0.f;

    int j = beg;
    for (; j + 1 < end; j += 2) {          // two independent load chains
        int sA = ebuf[j];
        int sB = ebuf[j + 1];
        float nsA = nsrc[sA];
        float nsB = nsrc[sB];
        union { uint4 u; __half2 h2[4]; } PA, PB;
        PA.u = *(const uint4*)&h[(long)sA * OUT_F + 8 * t];
        PB.u = *(const uint4*)&h[(long)sB * OUT_F + 8 * t];
        float2 fA0 = __half22float2(PA.h2[0]);
        float2 fA1 = __half22float2(PA.h2[1]);
        float2 fA2 = __half22float2(PA.h2[2]);
        float2 fA3 = __half22float2(PA.h2[3]);
        a0 = fmaf(fA0.x, nsA, a0); a1 = fmaf(fA0.y, nsA, a1);
        a2 = fmaf(fA1.x, nsA, a2); a3 = fmaf(fA1.y, nsA, a3);
        a4 = fmaf(fA2.x, nsA, a4); a5 = fmaf(fA2.y, nsA, a5);
        a6 = fmaf(fA3.x, nsA, a6); a7 = fmaf(fA3.y, nsA, a7);
        float2 fB0 = __half22float2(PB.h2[0]);
        float2 fB1 = __half22float2(PB.h2[1]);
        float2 fB2 = __half22float2(PB.h2[2]);
        float2 fB3 = __half22float2(PB.h2[3]);
        a0 = fmaf(fB0.x, nsB, a0); a1 = fmaf(fB0.y, nsB, a1);
        a2 = fmaf(fB1.x, nsB, a2); a3 = fmaf(fB1.y, nsB, a3);
        a4 = fmaf(fB2.x, nsB, a4); a5 = fmaf(fB2.y, nsB, a5);
        a6 = fmaf(fB3.x, nsB, a6); a7 = fmaf(fB3.y, nsB, a7);
    }
    if (j < end) {                         // tail edge
        int s = ebuf[j];
        float ns = nsrc[s];
        union { uint4 u; __half2 h2[4]; } P;
        P.u = *(const uint4*)&h[(long)s * OUT_F + 8 * t];
        float2 f0 = __half22float2(P.h2[0]);
        float2 f1 = __half22float2(P.h2[1]);
        float2 f2 = __half22float2(P.h2[2]);
        float2 f3 = __half22float2(P.h2[3]);
        a0 = fmaf(f0.x, ns, a0); a1 = fmaf(f0.y, ns, a1);
        a2 = fmaf(f1.x, ns, a2); a3 = fmaf(f1.y, ns, a3);
        a4 = fmaf(f2.x, ns, a4); a5 = fmaf(f2.y, ns, a5);
        a6 = fmaf(f3.x, ns, a6); a7 = fmaf(f3.y, ns, a7);
    }

    float nd = rsqrtf(fmaxf((float)m, 1.0f));
    float4 v0 = make_float4(a0 * nd, a1 * nd, a2 * nd, a3 * nd);
    float4 v1 = make_float4(a4 * nd, a5 * nd, a6 * nd, a7 * nd);
    float* op = &out[(long)d * OUT_F + 8 * t];
    *(float4*)op       = v0;    // wave writes 8 consecutive rows = 2 KB contiguous
    *(float4*)(op + 4) = v1;
}

extern "C" void kernel_launch(void* const* d_in, const int* in_sizes, int n_in,
                              void* d_out, int out_size, void* d_ws, size_t ws_size,
                              hipStream_t stream) {
    const float* feat = (const float*)d_in[0];
    const float* W    = (const float*)d_in[1];
    const int*   src  = (const int*)d_in[2];
    const int*   dst  = (const int*)d_in[3];
    float* out = (float*)d_out;

    const int n = in_sizes[0] / IN_F;     // 100000
    const int E = in_sizes[2];            // 600000

    // ---- workspace layout (~24 MB; ws is ~268 MB) ----
    char* wsb = (char*)d_ws;
    int* gcur_d = (int*)wsb;                              // NB
    int* gcur_s = gcur_d + NB;                            // NB
    float* nsrc = (float*)(gcur_s + NB);                  // n
    size_t pos = (((size_t)(2 * NB + n)) * 4 + 15) & ~(size_t)15;
    int2* off_deg = (int2*)(wsb + pos);                   // NB*512 int2 (1 MB)
    pos = (pos + (size_t)NB * 512 * 8 + 15) & ~(size_t)15;
    int* ebuf = (int*)(wsb + pos);                        // NB*CAP (3.9 MB)
    pos = (pos + (size_t)NB * CAP * 4 + 15) & ~(size_t)15;
    unsigned* bkt_d = (unsigned*)(wsb + pos);             // NB*CAP u32 (3.9 MB)
    pos = (pos + (size_t)NB * CAP * 4 + 15) & ~(size_t)15;
    unsigned short* bkt_s = (unsigned short*)(wsb + pos); // NB*CAP u16 (2.0 MB)
    pos = (pos + (size_t)NB * CAP * 2 + 15) & ~(size_t)15;
    __half* h = (__half*)(wsb + pos);                     // n*64 fp16 (12.8 MB)

    hipMemsetAsync(gcur_d, 0, 2 * NB * sizeof(int), stream);

    const int nbin  = (E + CHUNK - 1) / CHUNK;            // 293
    const int ngemm = (n + 127) / 128;                    // 782

    bin_gemm_kernel<<<nbin + ngemm, 256, 0, stream>>>(src, dst, gcur_d, gcur_s,
                                                      bkt_d, bkt_s, E, nbin,
                                                      feat, W, h, n);
    csr_kernel<<<NB, 256, 0, stream>>>(bkt_d, bkt_s, gcur_d, gcur_s,
                                       off_deg, ebuf, nsrc, n);
    gather_kernel<<<(n + 31) / 32, 256, 0, stream>>>(ebuf, off_deg, nsrc, h, out, n);
}

// Round 8
// 142.824 us; speedup vs baseline: 1.1620x; 1.0173x over previous
//
#include <hip/hip_runtime.h>
#include <hip/hip_fp16.h>

#define IN_F 128
#define OUT_F 64
#define NB    256     // node-range buckets, 512 nodes each
#define BSH   9
#define CAP   3840    // per-bucket capacity (lambda=2344, +31 sigma, proven R4-R7)
#define CHUNK 2048    // edges per bin block
#define KPF  136      // Fh k-pitch (bf16 elems)
#define KPW  144      // Wt k-pitch (bf16 elems)

using short8  = __attribute__((ext_vector_type(8))) short;
using float4v = __attribute__((ext_vector_type(4))) float;

static __device__ inline unsigned short f2bf(float x) {
    union { float f; unsigned u; } v; v.f = x;
    unsigned r = (v.u + 0x7fffu + ((v.u >> 16) & 1u)) >> 16;  // RN-even
    return (unsigned short)r;
}

// ---- fused pass 1: edge binning INTERLEAVED with GEMM ----------------------
// Role mapping is a Bresenham spread: block b is a bin block iff
// floor((b+1)*nbin/G) > floor(b*nbin/G). This mixes ~1 bin block (4 KB LDS,
// latency-heavy) with ~3 gemm blocks (53 KB LDS, MFMA-heavy) per CU so the
// two phases overlap instead of bin monopolizing the machine for one round.
// Inner code of both roles is byte-identical to the proven R7 kernel.
__global__ __launch_bounds__(256) void bin_gemm_kernel(
    const int* __restrict__ src, const int* __restrict__ dst,
    int* __restrict__ gcur_d, int* __restrict__ gcur_s,
    unsigned* __restrict__ bkt_d, unsigned short* __restrict__ bkt_s,
    int E, int nbin,
    const float* __restrict__ feat, const float* __restrict__ W,
    __half* __restrict__ h, int n)
{
    __shared__ union {
        struct { int hd[NB]; int hs[NB]; int based[NB]; int bases[NB]; } bin;
        struct { unsigned short Fh[128 * KPF]; unsigned short Wt[64 * KPW]; } gm;
    } smem;

    const int tid = threadIdx.x;
    const int b   = blockIdx.x;
    const int G   = gridDim.x;
    const int f   = (int)(((long)b       * nbin) / G);   // bin blocks before b
    const int c   = (int)(((long)(b + 1) * nbin) / G);
    const bool is_bin = (c > f);

    if (is_bin) {
        // ---------------- bin path (proven structure; bin block index = f) ---
        const int e0 = f * CHUNK;

        smem.bin.hd[tid] = 0; smem.bin.hs[tid] = 0;
        __syncthreads();

        int sv[8], dv[8];
        #pragma unroll
        for (int j = 0; j < 8; ++j) {
            int i = e0 + j * 256 + tid;          // coalesced
            if (i < E) { sv[j] = src[i]; dv[j] = dst[i]; }
            else       { sv[j] = -1;     dv[j] = -1; }
        }
        #pragma unroll
        for (int j = 0; j < 8; ++j) {
            if (dv[j] >= 0) {
                atomicAdd(&smem.bin.hd[dv[j] >> BSH], 1);
                atomicAdd(&smem.bin.hs[sv[j] >> BSH], 1);
            }
        }
        __syncthreads();

        int cd = smem.bin.hd[tid], cs = smem.bin.hs[tid];
        smem.bin.based[tid] = cd ? atomicAdd(&gcur_d[tid], cd) : 0;
        smem.bin.bases[tid] = cs ? atomicAdd(&gcur_s[tid], cs) : 0;
        smem.bin.hd[tid] = 0; smem.bin.hs[tid] = 0;   // reuse as local cursors
        __syncthreads();

        #pragma unroll
        for (int j = 0; j < 8; ++j) {
            if (dv[j] >= 0) {
                int bd = dv[j] >> BSH;
                int pd = atomicAdd(&smem.bin.hd[bd], 1) + smem.bin.based[bd];
                if (pd < CAP)
                    bkt_d[(size_t)bd * CAP + pd] =
                        (unsigned)sv[j] | ((unsigned)(dv[j] & 511) << 17);  // src < 2^17
                int bs = sv[j] >> BSH;
                int ps = atomicAdd(&smem.bin.hs[bs], 1) + smem.bin.bases[bs];
                if (ps < CAP) bkt_s[(size_t)bs * CAP + ps] = (unsigned short)(sv[j] & 511);
            }
        }
        return;
    }

    // ---------------- gemm path: h = feat @ W (raw fp16; ns applied in gather)
    unsigned short* Fh = smem.gm.Fh;
    unsigned short* Wt = smem.gm.Wt;
    const int row0 = (b - f) * 128;           // gemm block index = b - f

    {
        const float4* W4 = (const float4*)W;
        #pragma unroll
        for (int it = 0; it < 8; ++it) {
            int i4 = it * 256 + tid;
            int k  = i4 >> 4;
            int c4 = (i4 & 15) * 4;
            float4 wv = W4[i4];
            Wt[(c4 + 0) * KPW + k] = f2bf(wv.x);
            Wt[(c4 + 1) * KPW + k] = f2bf(wv.y);
            Wt[(c4 + 2) * KPW + k] = f2bf(wv.z);
            Wt[(c4 + 3) * KPW + k] = f2bf(wv.w);
        }
    }
    {
        const float4* F4 = (const float4*)feat;
        #pragma unroll
        for (int it = 0; it < 16; ++it) {
            int i4 = it * 256 + tid;
            int r  = i4 >> 5;
            int c4 = (i4 & 31) * 4;
            int gr = row0 + r; if (gr >= n) gr = n - 1;
            float4 v = F4[(long)gr * 32 + (i4 & 31)];
            ushort4 u;
            u.x = f2bf(v.x); u.y = f2bf(v.y); u.z = f2bf(v.z); u.w = f2bf(v.w);
            *(ushort4*)&Fh[r * KPF + c4] = u;
        }
    }
    __syncthreads();

    const int w  = tid >> 6;
    const int l  = tid & 63;
    const int ml = l & 15;
    const int q  = l >> 4;

    float4v acc[2][4];
    #pragma unroll
    for (int rt = 0; rt < 2; ++rt)
        #pragma unroll
        for (int ct = 0; ct < 4; ++ct)
            acc[rt][ct] = (float4v){0.f, 0.f, 0.f, 0.f};

    #pragma unroll
    for (int ks = 0; ks < 4; ++ks) {
        const int ko = ks * 32 + q * 8;
        short8 a0 = *(const short8*)&Fh[(w * 32 +  0 + ml) * KPF + ko];
        short8 a1 = *(const short8*)&Fh[(w * 32 + 16 + ml) * KPF + ko];
        short8 b0 = *(const short8*)&Wt[( 0 + ml) * KPW + ko];
        short8 b1 = *(const short8*)&Wt[(16 + ml) * KPW + ko];
        short8 b2 = *(const short8*)&Wt[(32 + ml) * KPW + ko];
        short8 b3 = *(const short8*)&Wt[(48 + ml) * KPW + ko];
        acc[0][0] = __builtin_amdgcn_mfma_f32_16x16x32_bf16(a0, b0, acc[0][0], 0, 0, 0);
        acc[0][1] = __builtin_amdgcn_mfma_f32_16x16x32_bf16(a0, b1, acc[0][1], 0, 0, 0);
        acc[0][2] = __builtin_amdgcn_mfma_f32_16x16x32_bf16(a0, b2, acc[0][2], 0, 0, 0);
        acc[0][3] = __builtin_amdgcn_mfma_f32_16x16x32_bf16(a0, b3, acc[0][3], 0, 0, 0);
        acc[1][0] = __builtin_amdgcn_mfma_f32_16x16x32_bf16(a1, b0, acc[1][0], 0, 0, 0);
        acc[1][1] = __builtin_amdgcn_mfma_f32_16x16x32_bf16(a1, b1, acc[1][1], 0, 0, 0);
        acc[1][2] = __builtin_amdgcn_mfma_f32_16x16x32_bf16(a1, b2, acc[1][2], 0, 0, 0);
        acc[1][3] = __builtin_amdgcn_mfma_f32_16x16x32_bf16(a1, b3, acc[1][3], 0, 0, 0);
    }

    #pragma unroll
    for (int rt = 0; rt < 2; ++rt) {
        #pragma unroll
        for (int reg = 0; reg < 4; ++reg) {
            int row = row0 + w * 32 + rt * 16 + q * 4 + reg;
            if (row < n) {
                #pragma unroll
                for (int ct = 0; ct < 4; ++ct)
                    h[(long)row * OUT_F + ct * 16 + ml] = __float2half(acc[rt][ct][reg]);
            }
        }
    }
}

// ---- pass 2: per-bucket counting sort + nsrc + off_deg (R5/R7's proven kernel)
__global__ __launch_bounds__(256) void csr_kernel(
    const unsigned* __restrict__ bkt_d, const unsigned short* __restrict__ bkt_s,
    const int* __restrict__ gcur_d, const int* __restrict__ gcur_s,
    int2* __restrict__ off_deg, int* __restrict__ ebuf, float* __restrict__ nsrc, int n)
{
    __shared__ int hist[512], curs[512], hist_s[512];
    __shared__ int wsum[4];
    const int b = blockIdx.x, tid = threadIdx.x;
    const int cnt   = min(gcur_d[b], CAP);
    const int cnt_s = min(gcur_s[b], CAP);

    hist[tid] = 0; hist[tid + 256] = 0;
    hist_s[tid] = 0; hist_s[tid + 256] = 0;
    __syncthreads();

    const unsigned* bp = bkt_d + (size_t)b * CAP;
    for (int i = tid; i < cnt; i += 256)
        atomicAdd(&hist[bp[i] >> 17], 1);
    // src-side histogram (outdeg for nodes in this bucket's range)
    for (int i = tid; i < cnt_s; i += 256)
        atomicAdd(&hist_s[bkt_s[(size_t)b * CAP + i]], 1);
    __syncthreads();

    // exclusive scan of hist[512]: wave shuffle scan + cross-wave combine
    int a0 = hist[2 * tid], a1 = hist[2 * tid + 1];
    int psum = a0 + a1;
    const int lane = tid & 63, w = tid >> 6;
    int x = psum;
    #pragma unroll
    for (int off = 1; off < 64; off <<= 1) {
        int y = __shfl_up(x, off);
        if (lane >= off) x += y;
    }
    if (lane == 63) wsum[w] = x;
    __syncthreads();
    int wbase = 0;
    for (int i = 0; i < w; ++i) wbase += wsum[i];
    int excl = x + wbase - psum;
    curs[2 * tid]     = excl;
    curs[2 * tid + 1] = excl + a0;
    off_deg[b * 512 + 2 * tid]     = make_int2(b * CAP + excl,      a0);
    off_deg[b * 512 + 2 * tid + 1] = make_int2(b * CAP + excl + a0, a1);
    __syncthreads();

    // sorted scatter straight to global; bucket window re-read is L1/L2-hot
    for (int i = tid; i < cnt; i += 256) {
        unsigned e = bp[i];
        int p = atomicAdd(&curs[e >> 17], 1);
        if (p < CAP) ebuf[b * CAP + p] = (int)(e & 0x1FFFFu);
    }

    // nsrc writeout: precomputed rsqrt so gather loads a plain float table
    int node = b * 512 + tid;
    if (node < n) nsrc[node] = rsqrtf(fmaxf((float)hist_s[tid], 1.0f));
    node += 256;
    if (node < n) nsrc[node] = rsqrtf(fmaxf((float)hist_s[tid + 256], 1.0f));
}

// ---- pull aggregation, stream-per-dst (R7's proven kernel) ------------------
__global__ __launch_bounds__(256) void gather_kernel(
    const int* __restrict__ ebuf, const int2* __restrict__ off_deg,
    const float* __restrict__ nsrc,
    const __half* __restrict__ h, float* __restrict__ out, int n)
{
    const int lane = threadIdx.x & 63;
    const int wv   = threadIdx.x >> 6;     // wave 0..3
    const int o    = lane >> 3;            // stream 0..7 -> dst offset in wave
    const int t    = lane & 7;             // col group: cols 8t..8t+7
    const int d    = blockIdx.x * 32 + wv * 8 + o;
    if (d >= n) return;

    int2 od = off_deg[d];
    const int beg = od.x, m = od.y, end = beg + m;

    float a0 = 0.f, a1 = 0.f, a2 = 0.f, a3 = 0.f;
    float a4 = 0.f, a5 = 0.f, a6 = 0.f, a7 = 0.f;

    int j = beg;
    for (; j + 1 < end; j += 2) {          // two independent load chains
        int sA = ebuf[j];
        int sB = ebuf[j + 1];
        float nsA = nsrc[sA];
        float nsB = nsrc[sB];
        union { uint4 u; __half2 h2[4]; } PA, PB;
        PA.u = *(const uint4*)&h[(long)sA * OUT_F + 8 * t];
        PB.u = *(const uint4*)&h[(long)sB * OUT_F + 8 * t];
        float2 fA0 = __half22float2(PA.h2[0]);
        float2 fA1 = __half22float2(PA.h2[1]);
        float2 fA2 = __half22float2(PA.h2[2]);
        float2 fA3 = __half22float2(PA.h2[3]);
        a0 = fmaf(fA0.x, nsA, a0); a1 = fmaf(fA0.y, nsA, a1);
        a2 = fmaf(fA1.x, nsA, a2); a3 = fmaf(fA1.y, nsA, a3);
        a4 = fmaf(fA2.x, nsA, a4); a5 = fmaf(fA2.y, nsA, a5);
        a6 = fmaf(fA3.x, nsA, a6); a7 = fmaf(fA3.y, nsA, a7);
        float2 fB0 = __half22float2(PB.h2[0]);
        float2 fB1 = __half22float2(PB.h2[1]);
        float2 fB2 = __half22float2(PB.h2[2]);
        float2 fB3 = __half22float2(PB.h2[3]);
        a0 = fmaf(fB0.x, nsB, a0); a1 = fmaf(fB0.y, nsB, a1);
        a2 = fmaf(fB1.x, nsB, a2); a3 = fmaf(fB1.y, nsB, a3);
        a4 = fmaf(fB2.x, nsB, a4); a5 = fmaf(fB2.y, nsB, a5);
        a6 = fmaf(fB3.x, nsB, a6); a7 = fmaf(fB3.y, nsB, a7);
    }
    if (j < end) {                         // tail edge
        int s = ebuf[j];
        float ns = nsrc[s];
        union { uint4 u; __half2 h2[4]; } P;
        P.u = *(const uint4*)&h[(long)s * OUT_F + 8 * t];
        float2 f0 = __half22float2(P.h2[0]);
        float2 f1 = __half22float2(P.h2[1]);
        float2 f2 = __half22float2(P.h2[2]);
        float2 f3 = __half22float2(P.h2[3]);
        a0 = fmaf(f0.x, ns, a0); a1 = fmaf(f0.y, ns, a1);
        a2 = fmaf(f1.x, ns, a2); a3 = fmaf(f1.y, ns, a3);
        a4 = fmaf(f2.x, ns, a4); a5 = fmaf(f2.y, ns, a5);
        a6 = fmaf(f3.x, ns, a6); a7 = fmaf(f3.y, ns, a7);
    }

    float nd = rsqrtf(fmaxf((float)m, 1.0f));
    float4 v0 = make_float4(a0 * nd, a1 * nd, a2 * nd, a3 * nd);
    float4 v1 = make_float4(a4 * nd, a5 * nd, a6 * nd, a7 * nd);
    float* op = &out[(long)d * OUT_F + 8 * t];
    *(float4*)op       = v0;    // wave writes 8 consecutive rows = 2 KB contiguous
    *(float4*)(op + 4) = v1;
}

extern "C" void kernel_launch(void* const* d_in, const int* in_sizes, int n_in,
                              void* d_out, int out_size, void* d_ws, size_t ws_size,
                              hipStream_t stream) {
    const float* feat = (const float*)d_in[0];
    const float* W    = (const float*)d_in[1];
    const int*   src  = (const int*)d_in[2];
    const int*   dst  = (const int*)d_in[3];
    float* out = (float*)d_out;

    const int n = in_sizes[0] / IN_F;     // 100000
    const int E = in_sizes[2];            // 600000

    // ---- workspace layout (~24 MB; ws is ~268 MB) ----
    char* wsb = (char*)d_ws;
    int* gcur_d = (int*)wsb;                              // NB
    int* gcur_s = gcur_d + NB;                            // NB
    float* nsrc = (float*)(gcur_s + NB);                  // n
    size_t pos = (((size_t)(2 * NB + n)) * 4 + 15) & ~(size_t)15;
    int2* off_deg = (int2*)(wsb + pos);                   // NB*512 int2 (1 MB)
    pos = (pos + (size_t)NB * 512 * 8 + 15) & ~(size_t)15;
    int* ebuf = (int*)(wsb + pos);                        // NB*CAP (3.9 MB)
    pos = (pos + (size_t)NB * CAP * 4 + 15) & ~(size_t)15;
    unsigned* bkt_d = (unsigned*)(wsb + pos);             // NB*CAP u32 (3.9 MB)
    pos = (pos + (size_t)NB * CAP * 4 + 15) & ~(size_t)15;
    unsigned short* bkt_s = (unsigned short*)(wsb + pos); // NB*CAP u16 (2.0 MB)
    pos = (pos + (size_t)NB * CAP * 2 + 15) & ~(size_t)15;
    __half* h = (__half*)(wsb + pos);                     // n*64 fp16 (12.8 MB)

    hipMemsetAsync(gcur_d, 0, 2 * NB * sizeof(int), stream);

    const int nbin  = (E + CHUNK - 1) / CHUNK;            // 293
    const int ngemm = (n + 127) / 128;                    // 782

    bin_gemm_kernel<<<nbin + ngemm, 256, 0, stream>>>(src, dst, gcur_d, gcur_s,
                                                      bkt_d, bkt_s, E, nbin,
                                                      feat, W, h, n);
    csr_kernel<<<NB, 256, 0, stream>>>(bkt_d, bkt_s, gcur_d, gcur_s,
                                       off_deg, ebuf, nsrc, n);
    gather_kernel<<<(n + 31) / 32, 256, 0, stream>>>(ebuf, off_deg, nsrc, h, out, n);
}